// Round 9
// baseline (230.491 us; speedup 1.0000x reference)
//
#include <hip/hip_runtime.h>
#include <hip/hip_bf16.h>

#define NN 4096
#define FIN 512
#define FOUT 64
#define NH 8
#define ALPHA 0.2f

typedef unsigned int uint;
typedef unsigned short ushort;
typedef unsigned char uchar;
typedef unsigned long long ull;
typedef __attribute__((ext_vector_type(8))) short short8;
typedef __attribute__((ext_vector_type(4))) float floatx4;

__device__ __forceinline__ float bf2f(ushort s) { return __uint_as_float(((uint)s) << 16); }
__device__ __forceinline__ ushort f2bf(float f) {
    uint u = __float_as_uint(f);
    u += 0x7fffu + ((u >> 16) & 1u);   // RNE
    return (ushort)(u >> 16);
}

// inline dtype probe: wave-uniform, deterministic (same 64 samples everywhere)
__device__ __forceinline__ int detect_bf16(const ushort* __restrict__ hraw) {
    int lane = threadIdx.x & 63;
    float a = fabsf(bf2f(hraw[2 * lane]));
    ull bal = __ballot(a >= 1e-3f && a <= 100.0f);
    return __popcll(bal) >= 32;
}

// ---------------------------------------------------------------------------
// Fused prep: [0,8192) packmask | [8192,9216) convert h (8 elem/thread) |
//             [9216,9248) transw.  Flag computed inline (no detect kernel).
// ---------------------------------------------------------------------------
#define PM_BLKS 8192
#define CV_BLKS 1024
#define TW_BLKS 32

__global__ __launch_bounds__(256) void prep_kernel(
    const int* __restrict__ mask, uchar* __restrict__ mb,
    const void* __restrict__ hraw, ushort* __restrict__ bh,
    const void* __restrict__ Wraw, ushort* __restrict__ WT)
{
    const int b = blockIdx.x, t = threadIdx.x;
    if (b < PM_BLKS) {
        size_t gid = (size_t)b * 256 + t;
        const int* p = mask + gid * 8;
        int4 aa = *(const int4*)p;
        int4 bb = *(const int4*)(p + 4);
        uint by = (uint)(aa.x > 0)        | ((uint)(aa.y > 0) << 1)
                | ((uint)(aa.z > 0) << 2) | ((uint)(aa.w > 0) << 3)
                | ((uint)(bb.x > 0) << 4) | ((uint)(bb.y > 0) << 5)
                | ((uint)(bb.z > 0) << 6) | ((uint)(bb.w > 0) << 7);
        mb[gid] = (uchar)by;
    } else if (b < PM_BLKS + CV_BLKS) {
        int isbf = detect_bf16((const ushort*)hraw);
        size_t e0 = ((size_t)(b - PM_BLKS) * 256 + t) * 8;
        if (isbf) {
            *(uint4*)(bh + e0) = *(const uint4*)((const ushort*)hraw + e0);
        } else {
            const float* s = (const float*)hraw + e0;
            float4 f0 = *(const float4*)s;
            float4 f1 = *(const float4*)(s + 4);
            uint4 o;
            o.x = (uint)f2bf(f0.x) | ((uint)f2bf(f0.y) << 16);
            o.y = (uint)f2bf(f0.z) | ((uint)f2bf(f0.w) << 16);
            o.z = (uint)f2bf(f1.x) | ((uint)f2bf(f1.y) << 16);
            o.w = (uint)f2bf(f1.z) | ((uint)f2bf(f1.w) << 16);
            *(uint4*)(bh + e0) = o;
        }
    } else {
        int isbf = detect_bf16((const ushort*)hraw);
        int b2 = b - PM_BLKS - CV_BLKS;
        int h = b2 >> 2, kq = b2 & 3;
        int o = t & 63, sub = t >> 6;
        int kbase = kq * 128 + sub * 32;
        uint pk[16];
#pragma unroll
        for (int kk = 0; kk < 32; kk += 2) {
            float v0, v1;
            size_t s0 = ((size_t)h * FIN + kbase + kk) * FOUT + o;
            size_t s1 = s0 + FOUT;
            if (isbf) { v0 = bf2f(((const ushort*)Wraw)[s0]); v1 = bf2f(((const ushort*)Wraw)[s1]); }
            else      { v0 = ((const float*)Wraw)[s0];        v1 = ((const float*)Wraw)[s1]; }
            pk[kk >> 1] = (uint)f2bf(v0) | ((uint)f2bf(v1) << 16);
        }
        ushort* dst = WT + ((size_t)h * FOUT + o) * FIN + kbase;
#pragma unroll
        for (int q = 0; q < 4; q++)
            *(uint4*)(dst + q * 8) = make_uint4(pk[q*4], pk[q*4+1], pk[q*4+2], pk[q*4+3]);
    }
}

// ---------------------------------------------------------------------------
// Stage 1 (MFMA): Wh = h*W + bW; WhT[h][o][n] bf16; el/er dots
// ---------------------------------------------------------------------------
__global__ __launch_bounds__(256) void wh_kernel(
    const ushort* __restrict__ hmat, const ushort* __restrict__ WT,
    const void* __restrict__ bWr, const void* __restrict__ alr,
    const void* __restrict__ arr, const void* __restrict__ bAr,
    const ushort* __restrict__ hraw,
    ushort* __restrict__ WhT, float* __restrict__ el, float* __restrict__ er)
{
    __shared__ __align__(16) ushort sT[64][72];
    const int t = threadIdx.x, lane = t & 63, wid = t >> 6;
    const int head = blockIdx.y, rbase = blockIdx.x * 64;
    const int lm = lane & 15, lq = lane >> 4;

    floatx4 C[4];
#pragma unroll
    for (int cg = 0; cg < 4; cg++) C[cg] = (floatx4){0.f, 0.f, 0.f, 0.f};

    const ushort* Ap = hmat + (size_t)(rbase + wid * 16 + lm) * FIN + lq * 8;
    const ushort* Bp = WT + (size_t)head * FOUT * FIN + (size_t)lm * FIN + lq * 8;

#pragma unroll
    for (int kc = 0; kc < 16; kc++) {
        short8 a = *(const short8*)(Ap + kc * 32);
#pragma unroll
        for (int cg = 0; cg < 4; cg++) {
            short8 b = *(const short8*)(Bp + (size_t)cg * 16 * FIN + kc * 32);
            C[cg] = __builtin_amdgcn_mfma_f32_16x16x32_bf16(a, b, C[cg], 0, 0, 0);
        }
    }

    const int isbf = detect_bf16(hraw);
    float bA = isbf ? bf2f(((const ushort*)bAr)[head]) : ((const float*)bAr)[head];
    float pel[4] = {0.f, 0.f, 0.f, 0.f}, per[4] = {0.f, 0.f, 0.f, 0.f};
#pragma unroll
    for (int cg = 0; cg < 4; cg++) {
        int o = head * FOUT + cg * 16 + lm;
        float bw = isbf ? bf2f(((const ushort*)bWr)[o]) : ((const float*)bWr)[o];
        float av = isbf ? bf2f(((const ushort*)alr)[o]) : ((const float*)alr)[o];
        float rv = isbf ? bf2f(((const ushort*)arr)[o]) : ((const float*)arr)[o];
        ushort pk[4];
#pragma unroll
        for (int r = 0; r < 4; r++) {
            float v = C[cg][r] + bw;
            pel[r] += v * av;
            per[r] += v * rv;
            pk[r] = f2bf(v);
        }
        ushort4 p4; p4.x = pk[0]; p4.y = pk[1]; p4.z = pk[2]; p4.w = pk[3];
        *(ushort4*)(&sT[cg * 16 + lm][wid * 16 + lq * 4]) = p4;
    }
#pragma unroll
    for (int off = 1; off < 16; off <<= 1) {
#pragma unroll
        for (int r = 0; r < 4; r++) {
            pel[r] += __shfl_xor(pel[r], off);
            per[r] += __shfl_xor(per[r], off);
        }
    }
    if (lm == 0) {
#pragma unroll
        for (int r = 0; r < 4; r++) {
            int row = rbase + wid * 16 + lq * 4 + r;
            el[(size_t)head * NN + row] = pel[r];
            er[(size_t)head * NN + row] = per[r] + bA;
        }
    }
    __syncthreads();
    {
        int o = t >> 2, ch = t & 3;
        uint4 v0 = *(const uint4*)(&sT[o][ch * 16]);
        uint4 v1 = *(const uint4*)(&sT[o][ch * 16 + 8]);
        ushort* d = WhT + ((size_t)head * FOUT + o) * NN + rbase + ch * 16;
        *(uint4*)d = v0;
        *(uint4*)(d + 8) = v1;
    }
}

// ---------------------------------------------------------------------------
// Stage 2 (R9): 128-thread blocks, each wave owns 32 i-rows (2 slabs) x 64 o.
// B-frags and v/z reads from LDS shared across both slabs -> LDS per output
// halved vs R8. v/z table built once per block in LDS (khv kernel gone).
// ---------------------------------------------------------------------------
__device__ __forceinline__ uint ppair(float v0, float v1, float z0, float z1,
                                      uint m2, float ui, float wi, float ti) {
    float p0 = (v0 >= ti) ? ui * v0 : wi * z0;
    float p1 = (v1 >= ti) ? ui * v1 : wi * z1;
    uint k0 = (uint)0 - (m2 & 1u);
    uint k1 = (uint)0 - ((m2 >> 1) & 1u);
    p0 = __uint_as_float(__float_as_uint(p0) & k0);
    p1 = __uint_as_float(__float_as_uint(p1) & k1);
    __hip_bfloat162 r = __float22bfloat162_rn(make_float2(p0, p1));
    return *(uint*)&r;
}

__device__ __forceinline__ short8 pgen8(float4 va, float4 vb, float4 za, float4 zb,
                                        uint mby, float ui, float wi, float ti) {
    union { uint4 u; short8 s; } c;
    c.u.x = ppair(va.x, va.y, za.x, za.y, mby,      ui, wi, ti);
    c.u.y = ppair(va.z, va.w, za.z, za.w, mby >> 2, ui, wi, ti);
    c.u.z = ppair(vb.x, vb.y, zb.x, zb.y, mby >> 4, ui, wi, ti);
    c.u.w = ppair(vb.z, vb.w, zb.z, zb.w, mby >> 6, ui, wi, ti);
    return c.s;
}

__global__ __launch_bounds__(128) void attn_kernel(
    const uchar* __restrict__ mb,      // [NN][512] bitmask
    const ushort* __restrict__ WhT,    // [H][FOUT][NN] bf16
    const float* __restrict__ el, const float* __restrict__ er,
    const ushort* __restrict__ hraw,
    void* __restrict__ outv)
{
    __shared__ __align__(16) ushort sB[2][64 * 72];  // B tile [o][j], dbuf
    __shared__ __align__(16) float sV[NN];           // e^{er-Kh}
    __shared__ __align__(16) float sZ[NN];           // e^{alpha(er-Kh)}
    __shared__ float sRed[2];

    const int t = threadIdx.x, lane = t & 63, wid = t >> 6;   // wid 0..1
    const int b = blockIdx.x;
    const int head = b & 7;                        // XCD swizzle
    const int ibase = (b >> 3) * 64;
    const int lm = lane & 15, lq = lane >> 4, sh8 = lq * 8;
    const int isbf = detect_bf16(hraw);

    // ---- prologue: Kh + v/z tables in LDS ----
    const float* erh = er + (size_t)head * NN;
    float mx = -3.0e38f;
    for (int j = t; j < NN; j += 128) mx = fmaxf(mx, erh[j]);
#pragma unroll
    for (int off = 32; off >= 1; off >>= 1) mx = fmaxf(mx, __shfl_xor(mx, off));
    if (lane == 0) sRed[wid] = mx;
    __syncthreads();
    const float kh = fmaxf(sRed[0], sRed[1]);
    for (int j = t; j < NN; j += 128) {
        float d = erh[j] - kh;
        sV[j] = __expf(d);
        sZ[j] = __expf(ALPHA * d);
    }

    // per-slab row constants (slab 0: rows +lm, slab 1: rows +16+lm)
    const int row0 = ibase + wid * 32 + lm;
    float x0 = el[(size_t)head * NN + row0] + kh;
    float x1 = el[(size_t)head * NN + row0 + 16] + kh;
    float Mi0 = fmaxf(x0, ALPHA * x0), Mi1 = fmaxf(x1, ALPHA * x1);
    float ui0 = __expf(x0 - Mi0), wi0 = __expf(ALPHA * x0 - Mi0), ti0 = __expf(-x0);
    float ui1 = __expf(x1 - Mi1), wi1 = __expf(ALPHA * x1 - Mi1), ti1 = __expf(-x1);

    const uchar* mrow0 = mb + (size_t)row0 * 512;
    const uchar* mrow1 = mb + (size_t)(row0 + 16) * 512;

    // staging: thread t -> B row so = t>>1, 32-j half sc
    const int so = t >> 1, sc = (t & 1) * 32;
    const ushort* gB = WhT + ((size_t)head * FOUT + so) * NN + sc;
    uint4 rB[4]; uint2 mkS0, mkS1;

    auto gload = [&](int j0) {
#pragma unroll
        for (int q = 0; q < 4; q++) rB[q] = *(const uint4*)(gB + j0 + q * 8);
        mkS0 = *(const uint2*)(mrow0 + (j0 >> 3));
        mkS1 = *(const uint2*)(mrow1 + (j0 >> 3));
    };
    auto lwrite = [&](int buf) {
#pragma unroll
        for (int q = 0; q < 4; q++)
            *(uint4*)(&sB[buf][so * 72 + sc + q * 8]) = rB[q];
    };

    const short8 ones = {0x3F80, 0x3F80, 0x3F80, 0x3F80, 0x3F80, 0x3F80, 0x3F80, 0x3F80};
    floatx4 C[2][4], Cd[2];
#pragma unroll
    for (int s = 0; s < 2; s++) {
        Cd[s] = (floatx4){0.f, 0.f, 0.f, 0.f};
#pragma unroll
        for (int g = 0; g < 4; g++) C[s][g] = (floatx4){0.f, 0.f, 0.f, 0.f};
    }

    auto compute = [&](int buf, int j0, uint2 mk0, uint2 mk1) {
        float4 va = *(const float4*)(&sV[j0 + sh8]);
        float4 vb = *(const float4*)(&sV[j0 + sh8 + 4]);
        float4 vc = *(const float4*)(&sV[j0 + 32 + sh8]);
        float4 vd = *(const float4*)(&sV[j0 + 32 + sh8 + 4]);
        float4 za = *(const float4*)(&sZ[j0 + sh8]);
        float4 zb = *(const float4*)(&sZ[j0 + sh8 + 4]);
        float4 zc = *(const float4*)(&sZ[j0 + 32 + sh8]);
        float4 zd = *(const float4*)(&sZ[j0 + 32 + sh8 + 4]);
        short8 a00 = pgen8(va, vb, za, zb, (mk0.x >> sh8) & 0xFFu, ui0, wi0, ti0);
        short8 a01 = pgen8(vc, vd, zc, zd, (mk0.y >> sh8) & 0xFFu, ui0, wi0, ti0);
        short8 a10 = pgen8(va, vb, za, zb, (mk1.x >> sh8) & 0xFFu, ui1, wi1, ti1);
        short8 a11 = pgen8(vc, vd, zc, zd, (mk1.y >> sh8) & 0xFFu, ui1, wi1, ti1);
        const ushort* base = &sB[buf][0];
        // half 0 (k = j0..j0+31)
        {
            short8 b0 = *(const short8*)(base + (0  + lm) * 72 + sh8);
            short8 b1 = *(const short8*)(base + (16 + lm) * 72 + sh8);
            short8 b2 = *(const short8*)(base + (32 + lm) * 72 + sh8);
            short8 b3 = *(const short8*)(base + (48 + lm) * 72 + sh8);
            Cd[0] = __builtin_amdgcn_mfma_f32_16x16x32_bf16(a00, ones, Cd[0], 0, 0, 0);
            Cd[1] = __builtin_amdgcn_mfma_f32_16x16x32_bf16(a10, ones, Cd[1], 0, 0, 0);
            C[0][0] = __builtin_amdgcn_mfma_f32_16x16x32_bf16(a00, b0, C[0][0], 0, 0, 0);
            C[1][0] = __builtin_amdgcn_mfma_f32_16x16x32_bf16(a10, b0, C[1][0], 0, 0, 0);
            C[0][1] = __builtin_amdgcn_mfma_f32_16x16x32_bf16(a00, b1, C[0][1], 0, 0, 0);
            C[1][1] = __builtin_amdgcn_mfma_f32_16x16x32_bf16(a10, b1, C[1][1], 0, 0, 0);
            C[0][2] = __builtin_amdgcn_mfma_f32_16x16x32_bf16(a00, b2, C[0][2], 0, 0, 0);
            C[1][2] = __builtin_amdgcn_mfma_f32_16x16x32_bf16(a10, b2, C[1][2], 0, 0, 0);
            C[0][3] = __builtin_amdgcn_mfma_f32_16x16x32_bf16(a00, b3, C[0][3], 0, 0, 0);
            C[1][3] = __builtin_amdgcn_mfma_f32_16x16x32_bf16(a10, b3, C[1][3], 0, 0, 0);
        }
        // half 1 (k = j0+32..j0+63)
        {
            short8 b0 = *(const short8*)(base + (0  + lm) * 72 + 32 + sh8);
            short8 b1 = *(const short8*)(base + (16 + lm) * 72 + 32 + sh8);
            short8 b2 = *(const short8*)(base + (32 + lm) * 72 + 32 + sh8);
            short8 b3 = *(const short8*)(base + (48 + lm) * 72 + 32 + sh8);
            Cd[0] = __builtin_amdgcn_mfma_f32_16x16x32_bf16(a01, ones, Cd[0], 0, 0, 0);
            Cd[1] = __builtin_amdgcn_mfma_f32_16x16x32_bf16(a11, ones, Cd[1], 0, 0, 0);
            C[0][0] = __builtin_amdgcn_mfma_f32_16x16x32_bf16(a01, b0, C[0][0], 0, 0, 0);
            C[1][0] = __builtin_amdgcn_mfma_f32_16x16x32_bf16(a11, b0, C[1][0], 0, 0, 0);
            C[0][1] = __builtin_amdgcn_mfma_f32_16x16x32_bf16(a01, b1, C[0][1], 0, 0, 0);
            C[1][1] = __builtin_amdgcn_mfma_f32_16x16x32_bf16(a11, b1, C[1][1], 0, 0, 0);
            C[0][2] = __builtin_amdgcn_mfma_f32_16x16x32_bf16(a01, b2, C[0][2], 0, 0, 0);
            C[1][2] = __builtin_amdgcn_mfma_f32_16x16x32_bf16(a11, b2, C[1][2], 0, 0, 0);
            C[0][3] = __builtin_amdgcn_mfma_f32_16x16x32_bf16(a01, b3, C[0][3], 0, 0, 0);
            C[1][3] = __builtin_amdgcn_mfma_f32_16x16x32_bf16(a11, b3, C[1][3], 0, 0, 0);
        }
    };

    // prologue staging: tile 0 into LDS, tile 1 into regs
    gload(0);
    lwrite(0);
    uint2 mk0 = mkS0, mk1 = mkS1;
    gload(64);
    __syncthreads();   // covers sV/sZ tables + sB[0]

    for (int it = 0; it < 64; it++) {
        compute(it & 1, it * 64, mk0, mk1);
        if (it < 63) {
            __syncthreads();
            lwrite((it + 1) & 1);
            mk0 = mkS0; mk1 = mkS1;
            gload(((it + 2) & 63) * 64);
            __syncthreads();
        }
    }

    // epilogue: normalize, elu, store
#pragma unroll
    for (int s = 0; s < 2; s++) {
#pragma unroll
        for (int r = 0; r < 4; r++) {
            int row = ibase + wid * 32 + s * 16 + lq * 4 + r;
            float inv = 1.f / Cd[s][r];
            float x0e = C[s][0][r] * inv; x0e = (x0e > 0.f) ? x0e : __expf(x0e) - 1.f;
            float x1e = C[s][1][r] * inv; x1e = (x1e > 0.f) ? x1e : __expf(x1e) - 1.f;
            float x2e = C[s][2][r] * inv; x2e = (x2e > 0.f) ? x2e : __expf(x2e) - 1.f;
            float x3e = C[s][3][r] * inv; x3e = (x3e > 0.f) ? x3e : __expf(x3e) - 1.f;
            size_t base = (size_t)row * (NH * FOUT) + head * FOUT + lm;
            if (isbf) {
                ushort* o = (ushort*)outv;
                o[base + 0]  = f2bf(x0e);
                o[base + 16] = f2bf(x1e);
                o[base + 32] = f2bf(x2e);
                o[base + 48] = f2bf(x3e);
            } else {
                float* o = (float*)outv;
                o[base + 0]  = x0e;
                o[base + 16] = x1e;
                o[base + 32] = x2e;
                o[base + 48] = x3e;
            }
        }
    }
}

extern "C" void kernel_launch(void* const* d_in, const int* in_sizes, int n_in,
                              void* d_out, int out_size, void* d_ws, size_t ws_size,
                              hipStream_t stream)
{
    const void* hraw = d_in[0];
    const int*  mask = (const int*)d_in[1];
    const void* Wraw = d_in[2];
    const void* bWr  = d_in[3];
    const void* alr  = d_in[4];
    const void* arr  = d_in[5];
    const void* bAr  = d_in[6];

    char* w = (char*)d_ws;
    ushort* bh   = (ushort*)w;                  w += (size_t)NN * FIN * 2;        // 4 MB
    ushort* WT   = (ushort*)w;                  w += (size_t)NH * FOUT * FIN * 2; // 512 KB
    ushort* WhT  = (ushort*)w;                  w += (size_t)NH * FOUT * NN * 2;  // 4 MB
    float*  el   = (float*)w;                   w += (size_t)NH * NN * 4;
    float*  er   = (float*)w;                   w += (size_t)NH * NN * 4;
    uchar*  mb   = (uchar*)w;                   w += (size_t)NN * 512;            // 2 MB

    prep_kernel<<<PM_BLKS + CV_BLKS + TW_BLKS, 256, 0, stream>>>(
        mask, mb, hraw, bh, Wraw, WT);
    wh_kernel<<<dim3(NN / 64, NH), 256, 0, stream>>>(bh, WT, bWr, alr, arr, bAr,
                                                     (const ushort*)hraw, WhT, el, er);
    attn_kernel<<<NN / 64 * NH, 128, 0, stream>>>(mb, WhT, el, er,
                                                  (const ushort*)hraw, d_out);
}

// Round 10
// 220.161 us; speedup vs baseline: 1.0469x; 1.0469x over previous
//
#include <hip/hip_runtime.h>
#include <hip/hip_bf16.h>

#define NN 4096
#define FIN 512
#define FOUT 64
#define NH 8
#define ALPHA 0.2f

typedef unsigned int uint;
typedef unsigned short ushort;
typedef unsigned char uchar;
typedef unsigned long long ull;
typedef __attribute__((ext_vector_type(8))) short short8;
typedef __attribute__((ext_vector_type(4))) float floatx4;

__device__ __forceinline__ float bf2f(ushort s) { return __uint_as_float(((uint)s) << 16); }
__device__ __forceinline__ ushort f2bf(float f) {
    uint u = __float_as_uint(f);
    u += 0x7fffu + ((u >> 16) & 1u);   // RNE
    return (ushort)(u >> 16);
}

// inline dtype probe: wave-uniform, deterministic (same 64 samples everywhere)
__device__ __forceinline__ int detect_bf16(const ushort* __restrict__ hraw) {
    int lane = threadIdx.x & 63;
    float a = fabsf(bf2f(hraw[2 * lane]));
    ull bal = __ballot(a >= 1e-3f && a <= 100.0f);
    return __popcll(bal) >= 32;
}

// ---------------------------------------------------------------------------
// Fused prep: [0,8192) packmask | [8192,9216) convert h (8 elem/thread) |
//             [9216,9248) transw   (unchanged from passing R9)
// ---------------------------------------------------------------------------
#define PM_BLKS 8192
#define CV_BLKS 1024
#define TW_BLKS 32

__global__ __launch_bounds__(256) void prep_kernel(
    const int* __restrict__ mask, uchar* __restrict__ mb,
    const void* __restrict__ hraw, ushort* __restrict__ bh,
    const void* __restrict__ Wraw, ushort* __restrict__ WT)
{
    const int b = blockIdx.x, t = threadIdx.x;
    if (b < PM_BLKS) {
        size_t gid = (size_t)b * 256 + t;
        const int* p = mask + gid * 8;
        int4 aa = *(const int4*)p;
        int4 bb = *(const int4*)(p + 4);
        uint by = (uint)(aa.x > 0)        | ((uint)(aa.y > 0) << 1)
                | ((uint)(aa.z > 0) << 2) | ((uint)(aa.w > 0) << 3)
                | ((uint)(bb.x > 0) << 4) | ((uint)(bb.y > 0) << 5)
                | ((uint)(bb.z > 0) << 6) | ((uint)(bb.w > 0) << 7);
        mb[gid] = (uchar)by;
    } else if (b < PM_BLKS + CV_BLKS) {
        int isbf = detect_bf16((const ushort*)hraw);
        size_t e0 = ((size_t)(b - PM_BLKS) * 256 + t) * 8;
        if (isbf) {
            *(uint4*)(bh + e0) = *(const uint4*)((const ushort*)hraw + e0);
        } else {
            const float* s = (const float*)hraw + e0;
            float4 f0 = *(const float4*)s;
            float4 f1 = *(const float4*)(s + 4);
            uint4 o;
            o.x = (uint)f2bf(f0.x) | ((uint)f2bf(f0.y) << 16);
            o.y = (uint)f2bf(f0.z) | ((uint)f2bf(f0.w) << 16);
            o.z = (uint)f2bf(f1.x) | ((uint)f2bf(f1.y) << 16);
            o.w = (uint)f2bf(f1.z) | ((uint)f2bf(f1.w) << 16);
            *(uint4*)(bh + e0) = o;
        }
    } else {
        int isbf = detect_bf16((const ushort*)hraw);
        int b2 = b - PM_BLKS - CV_BLKS;
        int h = b2 >> 2, kq = b2 & 3;
        int o = t & 63, sub = t >> 6;
        int kbase = kq * 128 + sub * 32;
        uint pk[16];
#pragma unroll
        for (int kk = 0; kk < 32; kk += 2) {
            float v0, v1;
            size_t s0 = ((size_t)h * FIN + kbase + kk) * FOUT + o;
            size_t s1 = s0 + FOUT;
            if (isbf) { v0 = bf2f(((const ushort*)Wraw)[s0]); v1 = bf2f(((const ushort*)Wraw)[s1]); }
            else      { v0 = ((const float*)Wraw)[s0];        v1 = ((const float*)Wraw)[s1]; }
            pk[kk >> 1] = (uint)f2bf(v0) | ((uint)f2bf(v1) << 16);
        }
        ushort* dst = WT + ((size_t)h * FOUT + o) * FIN + kbase;
#pragma unroll
        for (int q = 0; q < 4; q++)
            *(uint4*)(dst + q * 8) = make_uint4(pk[q*4], pk[q*4+1], pk[q*4+2], pk[q*4+3]);
    }
}

// per-head tables: Kh = max_j er'; v_j = e^{er-Kh}; z_j = e^{alpha(er-Kh)}
// (restored from passing R8 — R9's in-block tables blew up LDS/occupancy)
__global__ __launch_bounds__(256) void khv_kernel(const float* __restrict__ er,
                                                  float* __restrict__ Kh,
                                                  float* __restrict__ vt,
                                                  float* __restrict__ zt) {
    __shared__ float red[256];
    int h = blockIdx.x >> 3, sl = blockIdx.x & 7, t = threadIdx.x;
    float m = -3.0e38f;
    for (int j = t; j < NN; j += 256) m = fmaxf(m, er[(size_t)h * NN + j]);
    red[t] = m;
    __syncthreads();
    for (int s = 128; s >= 1; s >>= 1) {
        if (t < s) red[t] = fmaxf(red[t], red[t + s]);
        __syncthreads();
    }
    float kh = red[0];
    if (t == 0 && sl == 0) Kh[h] = kh;
    int j = sl * 512 + t;
#pragma unroll
    for (int q = 0; q < 2; q++, j += 256) {
        float d = er[(size_t)h * NN + j] - kh;
        vt[(size_t)h * NN + j] = __expf(d);
        zt[(size_t)h * NN + j] = __expf(ALPHA * d);
    }
}

// ---------------------------------------------------------------------------
// Stage 1 (MFMA): Wh = h*W + bW; WhT[h][o][n] bf16; el/er dots (unchanged)
// ---------------------------------------------------------------------------
__global__ __launch_bounds__(256) void wh_kernel(
    const ushort* __restrict__ hmat, const ushort* __restrict__ WT,
    const void* __restrict__ bWr, const void* __restrict__ alr,
    const void* __restrict__ arr, const void* __restrict__ bAr,
    const ushort* __restrict__ hraw,
    ushort* __restrict__ WhT, float* __restrict__ el, float* __restrict__ er)
{
    __shared__ __align__(16) ushort sT[64][72];
    const int t = threadIdx.x, lane = t & 63, wid = t >> 6;
    const int head = blockIdx.y, rbase = blockIdx.x * 64;
    const int lm = lane & 15, lq = lane >> 4;

    floatx4 C[4];
#pragma unroll
    for (int cg = 0; cg < 4; cg++) C[cg] = (floatx4){0.f, 0.f, 0.f, 0.f};

    const ushort* Ap = hmat + (size_t)(rbase + wid * 16 + lm) * FIN + lq * 8;
    const ushort* Bp = WT + (size_t)head * FOUT * FIN + (size_t)lm * FIN + lq * 8;

#pragma unroll
    for (int kc = 0; kc < 16; kc++) {
        short8 a = *(const short8*)(Ap + kc * 32);
#pragma unroll
        for (int cg = 0; cg < 4; cg++) {
            short8 b = *(const short8*)(Bp + (size_t)cg * 16 * FIN + kc * 32);
            C[cg] = __builtin_amdgcn_mfma_f32_16x16x32_bf16(a, b, C[cg], 0, 0, 0);
        }
    }

    const int isbf = detect_bf16(hraw);
    float bA = isbf ? bf2f(((const ushort*)bAr)[head]) : ((const float*)bAr)[head];
    float pel[4] = {0.f, 0.f, 0.f, 0.f}, per[4] = {0.f, 0.f, 0.f, 0.f};
#pragma unroll
    for (int cg = 0; cg < 4; cg++) {
        int o = head * FOUT + cg * 16 + lm;
        float bw = isbf ? bf2f(((const ushort*)bWr)[o]) : ((const float*)bWr)[o];
        float av = isbf ? bf2f(((const ushort*)alr)[o]) : ((const float*)alr)[o];
        float rv = isbf ? bf2f(((const ushort*)arr)[o]) : ((const float*)arr)[o];
        ushort pk[4];
#pragma unroll
        for (int r = 0; r < 4; r++) {
            float v = C[cg][r] + bw;
            pel[r] += v * av;
            per[r] += v * rv;
            pk[r] = f2bf(v);
        }
        ushort4 p4; p4.x = pk[0]; p4.y = pk[1]; p4.z = pk[2]; p4.w = pk[3];
        *(ushort4*)(&sT[cg * 16 + lm][wid * 16 + lq * 4]) = p4;
    }
#pragma unroll
    for (int off = 1; off < 16; off <<= 1) {
#pragma unroll
        for (int r = 0; r < 4; r++) {
            pel[r] += __shfl_xor(pel[r], off);
            per[r] += __shfl_xor(per[r], off);
        }
    }
    if (lm == 0) {
#pragma unroll
        for (int r = 0; r < 4; r++) {
            int row = rbase + wid * 16 + lq * 4 + r;
            el[(size_t)head * NN + row] = pel[r];
            er[(size_t)head * NN + row] = per[r] + bA;
        }
    }
    __syncthreads();
    {
        int o = t >> 2, ch = t & 3;
        uint4 v0 = *(const uint4*)(&sT[o][ch * 16]);
        uint4 v1 = *(const uint4*)(&sT[o][ch * 16 + 8]);
        ushort* d = WhT + ((size_t)head * FOUT + o) * NN + rbase + ch * 16;
        *(uint4*)d = v0;
        *(uint4*)(d + 8) = v1;
    }
}

// ---------------------------------------------------------------------------
// Stage 2 (R10): R8 pipeline + in-block j-split. 256 threads / 4 waves:
// wave w -> row-pair (w&1) [2 slabs x 16 rows] over j-half (w>>1) [32 tiles].
// 8 B-frag LDS reads feed 20 MFMA (2 slabs). Partial (C,Cd) combined across
// wave-pairs in LDS at the end. Same total waves as R8 (8/CU), ~half LDS ops.
// ---------------------------------------------------------------------------
__device__ __forceinline__ uint ppair(float v0, float v1, float z0, float z1,
                                      uint m2, float ui, float wi, float ti) {
    float p0 = (v0 >= ti) ? ui * v0 : wi * z0;
    float p1 = (v1 >= ti) ? ui * v1 : wi * z1;
    uint k0 = (uint)0 - (m2 & 1u);
    uint k1 = (uint)0 - ((m2 >> 1) & 1u);
    p0 = __uint_as_float(__float_as_uint(p0) & k0);
    p1 = __uint_as_float(__float_as_uint(p1) & k1);
    __hip_bfloat162 r = __float22bfloat162_rn(make_float2(p0, p1));
    return *(uint*)&r;
}

__device__ __forceinline__ short8 pgen8(float4 va, float4 vb, float4 za, float4 zb,
                                        uint mby, float ui, float wi, float ti) {
    union { uint4 u; short8 s; } c;
    c.u.x = ppair(va.x, va.y, za.x, za.y, mby,      ui, wi, ti);
    c.u.y = ppair(va.z, va.w, za.z, za.w, mby >> 2, ui, wi, ti);
    c.u.z = ppair(vb.x, vb.y, zb.x, zb.y, mby >> 4, ui, wi, ti);
    c.u.w = ppair(vb.z, vb.w, zb.z, zb.w, mby >> 6, ui, wi, ti);
    return c.s;
}

__global__ __launch_bounds__(256, 2) void attn_kernel(
    const uchar* __restrict__ mb,      // [NN][512] bitmask
    const ushort* __restrict__ WhT,    // [H][FOUT][NN] bf16
    const float* __restrict__ el, const float* __restrict__ Kh,
    const float* __restrict__ vt, const float* __restrict__ zt,
    const ushort* __restrict__ hraw,
    void* __restrict__ outv)
{
    __shared__ __align__(16) ushort sB[2][2][64 * 72];  // [j-half][buf][o][j]
    __shared__ float sv[2][2][64];
    __shared__ float sz[2][2][64];

    const int t = threadIdx.x, lane = t & 63, wid = t >> 6;
    const int b = blockIdx.x;
    const int head = b & 7;                        // XCD swizzle
    const int ibase = (b >> 3) * 64;
    const int lm = lane & 15, lq = lane >> 4, sh8 = lq * 8;
    const int jh = wid >> 1;                       // this wave's j-half
    const int rp = wid & 1;                        // row-pair: rows rp*32..rp*32+31
    const int jbase = jh * 2048;

    // per-lane row constants for the 2 slabs
    const float kh = Kh[head];
    const int row0 = ibase + rp * 32 + lm;
    float x0 = el[(size_t)head * NN + row0] + kh;
    float x1 = el[(size_t)head * NN + row0 + 16] + kh;
    float Mi0 = fmaxf(x0, ALPHA * x0), Mi1 = fmaxf(x1, ALPHA * x1);
    float ui0 = __expf(x0 - Mi0), wi0 = __expf(ALPHA * x0 - Mi0), ti0 = __expf(-x0);
    float ui1 = __expf(x1 - Mi1), wi1 = __expf(ALPHA * x1 - Mi1), ti1 = __expf(-x1);

    const uchar* mrow0 = mb + (size_t)row0 * 512 + (jbase >> 3);
    const uchar* mrow1 = mrow0 + (size_t)16 * 512;

    // staging: threads t<128 stage half 0, t>=128 stage half 1
    const int hf = t >> 7, tt = t & 127;
    const int so = tt >> 1, sc = (tt & 1) * 32;
    const ushort* gB = WhT + ((size_t)head * FOUT + so) * NN + hf * 2048 + sc;
    const float* gvt = vt + (size_t)head * NN + hf * 2048;
    const float* gzt = zt + (size_t)head * NN + hf * 2048;

    uint4 rB[4]; float rvz = 0.f; uint2 mkS0, mkS1;

    auto gload = [&](int j0) {                     // j0 = tile offset in half
#pragma unroll
        for (int q = 0; q < 4; q++) rB[q] = *(const uint4*)(gB + j0 + q * 8);
        rvz = (tt < 64) ? gvt[j0 + tt] : gzt[j0 + tt - 64];
        mkS0 = *(const uint2*)(mrow0 + (j0 >> 3));
        mkS1 = *(const uint2*)(mrow1 + (j0 >> 3));
    };
    auto lwrite = [&](int buf) {
#pragma unroll
        for (int q = 0; q < 4; q++)
            *(uint4*)(&sB[hf][buf][so * 72 + sc + q * 8]) = rB[q];
        if (tt < 64) sv[hf][buf][tt] = rvz; else sz[hf][buf][tt - 64] = rvz;
    };

    const short8 ones = {0x3F80, 0x3F80, 0x3F80, 0x3F80, 0x3F80, 0x3F80, 0x3F80, 0x3F80};
    floatx4 C[2][4], Cd[2];
#pragma unroll
    for (int s = 0; s < 2; s++) {
        Cd[s] = (floatx4){0.f, 0.f, 0.f, 0.f};
#pragma unroll
        for (int g = 0; g < 4; g++) C[s][g] = (floatx4){0.f, 0.f, 0.f, 0.f};
    }

    auto compute = [&](int buf, uint2 mk0, uint2 mk1) {
        float4 va = *(const float4*)(&sv[jh][buf][sh8]);
        float4 vb = *(const float4*)(&sv[jh][buf][sh8 + 4]);
        float4 vc = *(const float4*)(&sv[jh][buf][32 + sh8]);
        float4 vd = *(const float4*)(&sv[jh][buf][32 + sh8 + 4]);
        float4 za = *(const float4*)(&sz[jh][buf][sh8]);
        float4 zb = *(const float4*)(&sz[jh][buf][sh8 + 4]);
        float4 zc = *(const float4*)(&sz[jh][buf][32 + sh8]);
        float4 zd = *(const float4*)(&sz[jh][buf][32 + sh8 + 4]);
        short8 a00 = pgen8(va, vb, za, zb, (mk0.x >> sh8) & 0xFFu, ui0, wi0, ti0);
        short8 a01 = pgen8(vc, vd, zc, zd, (mk0.y >> sh8) & 0xFFu, ui0, wi0, ti0);
        short8 a10 = pgen8(va, vb, za, zb, (mk1.x >> sh8) & 0xFFu, ui1, wi1, ti1);
        short8 a11 = pgen8(vc, vd, zc, zd, (mk1.y >> sh8) & 0xFFu, ui1, wi1, ti1);
        const ushort* base = &sB[jh][buf][0];
        {   // k = cols 0..31 of tile
            short8 b0 = *(const short8*)(base + (0  + lm) * 72 + sh8);
            short8 b1 = *(const short8*)(base + (16 + lm) * 72 + sh8);
            short8 b2 = *(const short8*)(base + (32 + lm) * 72 + sh8);
            short8 b3 = *(const short8*)(base + (48 + lm) * 72 + sh8);
            Cd[0] = __builtin_amdgcn_mfma_f32_16x16x32_bf16(a00, ones, Cd[0], 0, 0, 0);
            Cd[1] = __builtin_amdgcn_mfma_f32_16x16x32_bf16(a10, ones, Cd[1], 0, 0, 0);
            C[0][0] = __builtin_amdgcn_mfma_f32_16x16x32_bf16(a00, b0, C[0][0], 0, 0, 0);
            C[1][0] = __builtin_amdgcn_mfma_f32_16x16x32_bf16(a10, b0, C[1][0], 0, 0, 0);
            C[0][1] = __builtin_amdgcn_mfma_f32_16x16x32_bf16(a00, b1, C[0][1], 0, 0, 0);
            C[1][1] = __builtin_amdgcn_mfma_f32_16x16x32_bf16(a10, b1, C[1][1], 0, 0, 0);
            C[0][2] = __builtin_amdgcn_mfma_f32_16x16x32_bf16(a00, b2, C[0][2], 0, 0, 0);
            C[1][2] = __builtin_amdgcn_mfma_f32_16x16x32_bf16(a10, b2, C[1][2], 0, 0, 0);
            C[0][3] = __builtin_amdgcn_mfma_f32_16x16x32_bf16(a00, b3, C[0][3], 0, 0, 0);
            C[1][3] = __builtin_amdgcn_mfma_f32_16x16x32_bf16(a10, b3, C[1][3], 0, 0, 0);
        }
        {   // k = cols 32..63 of tile
            short8 b0 = *(const short8*)(base + (0  + lm) * 72 + 32 + sh8);
            short8 b1 = *(const short8*)(base + (16 + lm) * 72 + 32 + sh8);
            short8 b2 = *(const short8*)(base + (32 + lm) * 72 + 32 + sh8);
            short8 b3 = *(const short8*)(base + (48 + lm) * 72 + 32 + sh8);
            Cd[0] = __builtin_amdgcn_mfma_f32_16x16x32_bf16(a01, ones, Cd[0], 0, 0, 0);
            Cd[1] = __builtin_amdgcn_mfma_f32_16x16x32_bf16(a11, ones, Cd[1], 0, 0, 0);
            C[0][0] = __builtin_amdgcn_mfma_f32_16x16x32_bf16(a01, b0, C[0][0], 0, 0, 0);
            C[1][0] = __builtin_amdgcn_mfma_f32_16x16x32_bf16(a11, b0, C[1][0], 0, 0, 0);
            C[0][1] = __builtin_amdgcn_mfma_f32_16x16x32_bf16(a01, b1, C[0][1], 0, 0, 0);
            C[1][1] = __builtin_amdgcn_mfma_f32_16x16x32_bf16(a11, b1, C[1][1], 0, 0, 0);
            C[0][2] = __builtin_amdgcn_mfma_f32_16x16x32_bf16(a01, b2, C[0][2], 0, 0, 0);
            C[1][2] = __builtin_amdgcn_mfma_f32_16x16x32_bf16(a11, b2, C[1][2], 0, 0, 0);
            C[0][3] = __builtin_amdgcn_mfma_f32_16x16x32_bf16(a01, b3, C[0][3], 0, 0, 0);
            C[1][3] = __builtin_amdgcn_mfma_f32_16x16x32_bf16(a11, b3, C[1][3], 0, 0, 0);
        }
    };

    // prologue: stage tile 0, prefetch tile 1
    gload(0);
    lwrite(0);
    uint2 mk0c = mkS0, mk1c = mkS1;
    gload(64);
    __syncthreads();

    for (int it = 0; it < 32; it++) {
        compute(it & 1, mk0c, mk1c);
        if (it < 31) {
            __syncthreads();
            lwrite((it + 1) & 1);
            mk0c = mkS0; mk1c = mkS1;
            gload(((it + 2) & 31) * 64);
            __syncthreads();
        }
    }

    // ---- combine partials across wave-pairs (jh=1 -> jh=0) via LDS ----
    __syncthreads();
    float* dumpf = (float*)&sB[0][0][0];   // 36 KB scratch, frag layout float4
    if (jh == 1) {
#pragma unroll
        for (int s = 0; s < 2; s++) {
            int g = rp * 2 + s;
#pragma unroll
            for (int f = 0; f < 4; f++)
                *(floatx4*)&dumpf[4 * ((g * 5 + f) * 64 + lane)] = C[s][f];
            *(floatx4*)&dumpf[4 * ((g * 5 + 4) * 64 + lane)] = Cd[s];
        }
    }
    __syncthreads();
    if (jh == 0) {
        const int isbf = detect_bf16(hraw);
#pragma unroll
        for (int s = 0; s < 2; s++) {
            int g = rp * 2 + s;
#pragma unroll
            for (int f = 0; f < 4; f++)
                C[s][f] += *(const floatx4*)&dumpf[4 * ((g * 5 + f) * 64 + lane)];
            Cd[s] += *(const floatx4*)&dumpf[4 * ((g * 5 + 4) * 64 + lane)];
        }
#pragma unroll
        for (int s = 0; s < 2; s++) {
#pragma unroll
            for (int r = 0; r < 4; r++) {
                int row = ibase + rp * 32 + s * 16 + lq * 4 + r;
                float inv = 1.f / Cd[s][r];
                float x0e = C[s][0][r] * inv; x0e = (x0e > 0.f) ? x0e : __expf(x0e) - 1.f;
                float x1e = C[s][1][r] * inv; x1e = (x1e > 0.f) ? x1e : __expf(x1e) - 1.f;
                float x2e = C[s][2][r] * inv; x2e = (x2e > 0.f) ? x2e : __expf(x2e) - 1.f;
                float x3e = C[s][3][r] * inv; x3e = (x3e > 0.f) ? x3e : __expf(x3e) - 1.f;
                size_t base = (size_t)row * (NH * FOUT) + head * FOUT + lm;
                if (isbf) {
                    ushort* o = (ushort*)outv;
                    o[base + 0]  = f2bf(x0e);
                    o[base + 16] = f2bf(x1e);
                    o[base + 32] = f2bf(x2e);
                    o[base + 48] = f2bf(x3e);
                } else {
                    float* o = (float*)outv;
                    o[base + 0]  = x0e;
                    o[base + 16] = x1e;
                    o[base + 32] = x2e;
                    o[base + 48] = x3e;
                }
            }
        }
    }
}

extern "C" void kernel_launch(void* const* d_in, const int* in_sizes, int n_in,
                              void* d_out, int out_size, void* d_ws, size_t ws_size,
                              hipStream_t stream)
{
    const void* hraw = d_in[0];
    const int*  mask = (const int*)d_in[1];
    const void* Wraw = d_in[2];
    const void* bWr  = d_in[3];
    const void* alr  = d_in[4];
    const void* arr  = d_in[5];
    const void* bAr  = d_in[6];

    char* w = (char*)d_ws;
    ushort* bh   = (ushort*)w;                  w += (size_t)NN * FIN * 2;        // 4 MB
    ushort* WT   = (ushort*)w;                  w += (size_t)NH * FOUT * FIN * 2; // 512 KB
    ushort* WhT  = (ushort*)w;                  w += (size_t)NH * FOUT * NN * 2;  // 4 MB
    float*  el   = (float*)w;                   w += (size_t)NH * NN * 4;
    float*  er   = (float*)w;                   w += (size_t)NH * NN * 4;
    float*  Kh   = (float*)w;                   w += 64;
    float*  vt   = (float*)w;                   w += (size_t)NH * NN * 4;
    float*  zt   = (float*)w;                   w += (size_t)NH * NN * 4;
    uchar*  mb   = (uchar*)w;                   w += (size_t)NN * 512;            // 2 MB

    prep_kernel<<<PM_BLKS + CV_BLKS + TW_BLKS, 256, 0, stream>>>(
        mask, mb, hraw, bh, Wraw, WT);
    wh_kernel<<<dim3(NN / 64, NH), 256, 0, stream>>>(bh, WT, bWr, alr, arr, bAr,
                                                     (const ushort*)hraw, WhT, el, er);
    khv_kernel<<<64, 256, 0, stream>>>(er, Kh, vt, zt);
    attn_kernel<<<NN / 64 * NH, 256, 0, stream>>>(mb, WhT, el, Kh, vt, zt,
                                                  (const ushort*)hraw, d_out);
}